// Round 5
// baseline (987.702 us; speedup 1.0000x reference)
//
#include <hip/hip_runtime.h>

// GoL CNN v6 (resubmit — round 4 was an infra failure; audit found no defect):
// per-wave software pipeline.
//  - F-register double-buffer: B-fragments for channel c+1 are gathered from
//    LDS while channel c's MFMAs run on register-resident fragments -> LDS
//    pipe and matrix pipe overlap within a single wave.
//  - ring-8 rowbuf, barrier every 4 channels (8/layer): group g reads slots
//    (4g..4g+3)&7 and writes (4g+4..4g+7)&7 -> disjoint halves, race-free.
//  - A-fragment prefetch distance 1 (register alternation, no copies).
// Math identical to v4/v5 (consecutive-ky, 12 gathers / 16 MFMA per wave/c).

typedef _Float16 f16;
typedef _Float16 f16x8 __attribute__((ext_vector_type(8)));
typedef float f32x4 __attribute__((ext_vector_type(4)));
typedef float f32x16 __attribute__((ext_vector_type(16)));

// iterated wrap-pad index map, j in [0,94): middle j-31; borders alternate.
__device__ __forceinline__ int mwrap(int j) {
  int t = j - 31;
  if ((unsigned)t <= 31u) return t;          // middle
  if (t < 0) return (j & 1) ? 0 : 31;        // left border
  return (j & 1) ? 0 : 31;                   // right border
}

// hpad layout: [16b][32ch][32y][96x] f16 (x' in [0,94) valid)
// Wf frag-major: per layer, chunk=(c*32+ky)*2+kxh, then [lane(64)][8 f16]
//   lane: co=lane&31, s=lane>>5; elements w[co][c][ky][kxh*16+s*8+j]

// Gather the 12 B-fragments of channel cc (ring slot cc&7) into FD.
#define LOADF(FD, cc)                                                       \
  {                                                                         \
    const int so_ = ((cc) & 7) * 6144;                                      \
    _Pragma("unroll")                                                       \
    for (int j_ = 0; j_ < 6; ++j_) {                                        \
      const int* Rj_ = (const int*)(lds0 + V[j_] + so_);                    \
      int4 t0_, t1_;                                                        \
      t0_.x = Rj_[0]; t0_.y = Rj_[1]; t0_.z = Rj_[2]; t0_.w = Rj_[3];       \
      t1_.x = Rj_[8]; t1_.y = Rj_[9]; t1_.z = Rj_[10]; t1_.w = Rj_[11];     \
      FD[j_][0] = __builtin_bit_cast(f16x8, t0_);                           \
      FD[j_][1] = __builtin_bit_cast(f16x8, t1_);                           \
    }                                                                       \
  }

// 16 MFMAs consuming register-resident fragments (no LDS access).
#define MFMAC(AUSE, FD)                                                     \
  {                                                                         \
    _Pragma("unroll")                                                       \
    for (int kyi_ = 0; kyi_ < 4; ++kyi_) {                                  \
      _Pragma("unroll")                                                     \
      for (int kxh_ = 0; kxh_ < 2; ++kxh_) {                                \
        const f16x8 a_ = AUSE[kyi_ * 2 + kxh_];                             \
        acc0 = __builtin_amdgcn_mfma_f32_32x32x16_f16(a_, FD[kyi_][kxh_],   \
                                                      acc0, 0, 0, 0);       \
        acc1 = __builtin_amdgcn_mfma_f32_32x32x16_f16(a_, FD[kyi_ + 2][kxh_],\
                                                      acc1, 0, 0, 0);       \
      }                                                                     \
    }                                                                       \
  }

// Producer barrier: drain LDS ops only; VMEM (weight/stage loads) stays in
// flight across the barrier. sched_barrier pins the region (rule #18).
#define GOLBAR()                                       \
  asm volatile("s_waitcnt lgkmcnt(0)" ::: "memory");   \
  __builtin_amdgcn_sched_barrier(0);                   \
  __builtin_amdgcn_s_barrier();

template <int CIN, bool RELU, bool PRE>
__global__ __launch_bounds__(512, 2) void gemm3(
    const void* __restrict__ Wv,       // PRE: f16 frag-major; else fp32 raw
    const f16* __restrict__ hp_in,     // [16][CIN][32][96]
    const float* __restrict__ bias,    // [32]
    f16* __restrict__ hp_out) {        // [16][32][32][96]
  __shared__ __align__(16) f16 rowbuf[8][32][96];  // 48 KB ring (slot=6144 B)
  __shared__ float Red[8][2][1024];                // 64 KB

  const int tid = threadIdx.x;
  const int lane = tid & 63;
  const int w = tid >> 6;        // wave 0..7: owns ky in {4w..4w+3}
  const int ox = lane & 31;      // B n-index / A m-index (co)
  const int s = lane >> 5;       // k-half within mfma

  const int pair0 = blockIdx.x * 2;
  const int b = pair0 >> 5;
  const int oy0 = pair0 & 31;    // pair0 even -> oy0, oy0+1 same batch

  // row staging decode: 384 units of f16x8 cover 32 rows x 96 (waves 0-5)
  const int rrow = tid / 12, rseg = tid - rrow * 12;  // valid if tid<384

  // input rows needed by this wave (loop-invariant across c):
  // acc0 (row oy0):   y = mwrap(2*oy0 + 4w + kyi)      -> j = kyi
  // acc1 (row oy0+1): y = mwrap(2*oy0 + 2 + 4w + kyi)  -> j = kyi+2
  const int bi = ox + 4 * s;
  char* lds0 = (char*)&rowbuf[0][0][0];
  int V[6];
#pragma unroll
  for (int j = 0; j < 6; ++j)
    V[j] = mwrap(2 * oy0 + 4 * w + j) * 192 + bi * 4;  // byte offset in slot

  const int wroff = rrow * 192 + rseg * 16;  // staging write byte offset

  f32x16 acc0 = {}, acc1 = {};   // per pair
  f16x8 A0[8], A1[8];
  f16x8 F0[6][2], F1[6][2];
  f16x8 stgA = {}, stgB = {}, stgC = {}, stgD = {};

  auto loadA = [&](int c, f16x8* dst) {
#pragma unroll
    for (int kyi = 0; kyi < 4; ++kyi) {
#pragma unroll
      for (int kxh = 0; kxh < 2; ++kxh) {
        const int ky = 4 * w + kyi;
        const int chunk = (c * 32 + ky) * 2 + kxh;
        if constexpr (PRE) {
          const f16* Wl = (const f16*)Wv;
          dst[kyi * 2 + kxh] = *(const f16x8*)(Wl + (size_t)chunk * 512 + lane * 8);
        } else {
          const float* Wl = (const float*)Wv;
          const float* sp = Wl + (((size_t)(ox * CIN + c) * 32 + ky) * 32 + kxh * 16 + s * 8);
          f32x4 u0 = *(const f32x4*)sp;
          f32x4 u1 = *(const f32x4*)(sp + 4);
          f16x8 v;
          v[0] = (f16)u0[0]; v[1] = (f16)u0[1]; v[2] = (f16)u0[2]; v[3] = (f16)u0[3];
          v[4] = (f16)u1[0]; v[5] = (f16)u1[1]; v[6] = (f16)u1[2]; v[7] = (f16)u1[3];
          dst[kyi * 2 + kxh] = v;
        }
      }
    }
  };
  auto loadRowTo = [&](int c, f16x8& dst) {
    if (tid < 384)
      dst = *(const f16x8*)(hp_in + ((size_t)(b * CIN + c) * 32 + rrow) * 96 + rseg * 8);
  };
  auto writeSlot = [&](int slot, const f16x8& src) {
    if (tid < 384) *(f16x8*)(lds0 + slot * 6144 + wroff) = src;
  };

  if constexpr (CIN == 1) {
    loadRowTo(0, stgA);
    writeSlot(0, stgA);
    loadA(0, A0);
    __syncthreads();
    LOADF(F0, 0);
    MFMAC(A0, F0);
  } else {
    static_assert(CIN % 4 == 0, "CIN must be 1 or a multiple of 4");
    loadRowTo(0, stgA); loadRowTo(1, stgB);
    loadRowTo(2, stgC); loadRowTo(3, stgD);
    writeSlot(0, stgA); writeSlot(1, stgB);
    writeSlot(2, stgC); writeSlot(3, stgD);
    loadA(0, A0);
    __syncthreads();

#pragma unroll 1
    for (int g = 0; g < CIN / 4; ++g) {
      const int t0 = 4 * g;
      const bool more = (t0 + 4 < CIN);
      if (more) {  // stage next 4 channels (landing ~3 channels later)
        loadRowTo(t0 + 4, stgA); loadRowTo(t0 + 5, stgB);
        loadRowTo(t0 + 6, stgC); loadRowTo(t0 + 7, stgD);
      }
      LOADF(F0, t0);             // c0 fragments (group-boundary read)
      loadA(t0 + 1, A1);
      LOADF(F1, t0 + 1);         // c1 prefetch overlaps c0 MFMAs
      MFMAC(A0, F0);             // c0
      LOADF(F0, t0 + 2);         // c2 prefetch overlaps c1 MFMAs
      loadA(t0 + 2, A0);
      MFMAC(A1, F1);             // c1
      LOADF(F1, t0 + 3);         // c3 prefetch overlaps c2 MFMAs
      loadA(t0 + 3, A1);
      MFMAC(A0, F0);             // c2
      if (more) {                // writes overlap c3 MFMAs; target other half
        writeSlot((t0 + 4) & 7, stgA); writeSlot((t0 + 5) & 7, stgB);
        writeSlot((t0 + 6) & 7, stgC); writeSlot((t0 + 7) & 7, stgD);
        loadA(t0 + 4, A0);
      }
      MFMAC(A1, F1);             // c3
      GOLBAR();
    }
  }

  // one-shot 8-way K reduction: every wave dumps, all 512 threads re-reduce
#pragma unroll
  for (int r = 0; r < 16; ++r) {
    Red[w][0][r * 64 + lane] = acc0[r];
    Red[w][1][r * 64 + lane] = acc1[r];
  }
  __syncthreads();

#pragma unroll
  for (int k4 = 0; k4 < 4; ++k4) {
    const int o = tid + 512 * k4;          // 2048 outputs: [p][co][ox]
    const int p = o >> 10, co = (o >> 5) & 31, oxx = o & 31;
    const int idx = ((co & 3) + 4 * (co >> 3)) * 64 + ((co >> 2) & 1) * 32 + oxx;
    float v = bias[co];
#pragma unroll
    for (int w8 = 0; w8 < 8; ++w8) v += Red[w8][p][idx];
    if (RELU) v = fmaxf(v, 0.f);
    const f16 hv = (f16)v;
    f16* base = hp_out + ((size_t)(b * 32 + co) * 32 + (oy0 + p)) * 96;
    base[oxx + 31] = hv;
    if (oxx == 0) {
#pragma unroll
      for (int j = 1; j <= 29; j += 2) base[j] = hv;
#pragma unroll
      for (int j = 63; j <= 93; j += 2) base[j] = hv;
    }
    if (oxx == 31) {
#pragma unroll
      for (int j = 0; j <= 30; j += 2) base[j] = hv;
#pragma unroll
      for (int j = 64; j <= 92; j += 2) base[j] = hv;
    }
  }
}

// x (fp32 [16][1][32][32]) -> xpad f16 [16][1][32][96]
__global__ void pad_x_kernel(const float* __restrict__ x, f16* __restrict__ xp) {
  const int i = blockIdx.x * 256 + threadIdx.x;  // 16*32*94 = 48128
  if (i >= 48128) return;
  const int bq = i / 3008, r = i - bq * 3008;
  const int y = r / 94, j = r - y * 94;
  xp[bq * 3072 + y * 96 + j] = (f16)x[(bq * 32 + y) * 32 + mwrap(j)];
}

// build frag-major f16 weights: in_w (64 chunks) + 20 hidden layers (2048 each)
__global__ void convert_w3(const float* __restrict__ in_w,
                           const float* __restrict__ convs_w,
                           f16* __restrict__ WfIn, f16* __restrict__ WfH) {
  const int total = 4096 + 20 * 131072;  // units of (chunk,lane)
  for (int g = blockIdx.x * blockDim.x + threadIdx.x; g < total;
       g += gridDim.x * blockDim.x) {
    const float* src;
    f16* dst;
    int chunk, lanE, c, ky, kxh;
    if (g < 4096) {
      chunk = g >> 6; lanE = g & 63;
      kxh = chunk & 1; ky = chunk >> 1; c = 0;
      const int co = lanE & 31, ss = lanE >> 5;
      src = in_w + ((size_t)(co * 1 + 0) * 32 + ky) * 32 + kxh * 16 + ss * 8;
      dst = WfIn + (size_t)chunk * 512 + lanE * 8;
    } else {
      const int h = g - 4096;
      const int layer = h >> 17, r = h & 131071;
      chunk = r >> 6; lanE = r & 63;
      kxh = chunk & 1;
      const int t = chunk >> 1;
      ky = t & 31; c = t >> 5;
      const int co = lanE & 31, ss = lanE >> 5;
      src = convs_w + (size_t)layer * 1048576 +
            ((size_t)(co * 32 + c) * 32 + ky) * 32 + kxh * 16 + ss * 8;
      dst = WfH + (size_t)layer * 1048576 + (size_t)chunk * 512 + lanE * 8;
    }
    f32x4 u0 = *(const f32x4*)src;
    f32x4 u1 = *(const f32x4*)(src + 4);
    f16x8 v;
    v[0] = (f16)u0[0]; v[1] = (f16)u0[1]; v[2] = (f16)u0[2]; v[3] = (f16)u0[3];
    v[4] = (f16)u1[0]; v[5] = (f16)u1[1]; v[6] = (f16)u1[2]; v[7] = (f16)u1[3];
    *(f16x8*)dst = v;
  }
}

// 1x1 out conv from hpad final: out[b][0][oy][ox] fp32
__global__ void out_conv3(const f16* __restrict__ hp,
                          const float* __restrict__ ow,
                          const float* __restrict__ ob,
                          float* __restrict__ out) {
  const int o = blockIdx.x * 256 + threadIdx.x;  // 16384
  const int b = o >> 10, oy = (o >> 5) & 31, oxx = o & 31;
  float s = ob[0];
#pragma unroll
  for (int c = 0; c < 32; ++c)
    s += ow[c] * (float)hp[((size_t)(b * 32 + c) * 32 + oy) * 96 + oxx + 31];
  out[o] = s;
}

extern "C" void kernel_launch(void* const* d_in, const int* in_sizes, int n_in,
                              void* d_out, int out_size, void* d_ws,
                              size_t ws_size, hipStream_t stream) {
  const float* x = (const float*)d_in[0];
  const float* in_w = (const float*)d_in[1];
  const float* in_b = (const float*)d_in[2];
  const float* convs_w = (const float*)d_in[3];
  const float* convs_b = (const float*)d_in[4];
  const float* out_w = (const float*)d_in[5];
  const float* out_b = (const float*)d_in[6];
  float* out = (float*)d_out;

  char* ws = (char*)d_ws;
  f16* xpad = (f16*)ws;                               //    98,304 B
  f16* hpA = (f16*)(ws + 98304);                      // 3,145,728 B
  f16* hpB = (f16*)(ws + 98304 + 3145728);            // 3,145,728 B
  f16* WfIn = (f16*)(ws + 6389760);                   //    65,536 B
  f16* WfH = (f16*)(ws + 6455296);                    // 41,943,040 B
  const bool pre = (ws_size >= 48398336ull);

  pad_x_kernel<<<188, 256, 0, stream>>>(x, xpad);
  if (pre) convert_w3<<<2048, 256, 0, stream>>>(in_w, convs_w, WfIn, WfH);

  if (pre)
    gemm3<1, false, true><<<256, 512, 0, stream>>>(WfIn, xpad, in_b, hpA);
  else
    gemm3<1, false, false><<<256, 512, 0, stream>>>(in_w, xpad, in_b, hpA);

  for (int l = 0; l < 20; ++l) {
    const f16* cur = (l % 2 == 0) ? hpA : hpB;
    f16* nxt = (l % 2 == 0) ? hpB : hpA;
    if (pre)
      gemm3<32, true, true><<<256, 512, 0, stream>>>(
          WfH + (size_t)l * 1048576, cur, convs_b + 32 * l, nxt);
    else
      gemm3<32, true, false><<<256, 512, 0, stream>>>(
          convs_w + (size_t)l * 1048576, cur, convs_b + 32 * l, nxt);
  }

  // after l=19 (odd): output in hpA
  out_conv3<<<64, 256, 0, stream>>>(hpA, out_w, out_b, out);
}